// Round 11
// baseline (522.461 us; speedup 1.0000x reference)
//
#include <hip/hip_runtime.h>
#include <math.h>

// MultiPerspectiveMatch on MI355X — round 11: TWO kernels.
// r10 confirmed ~20us/launch fixed cost -> eliminate k_prep and k_out entirely:
//  K1 k_main  = maxpool + relwq + gemm1, all input-only:
//    - maxpool self-computes M2_c + iq[j] in f32 (more accurate than the old
//      bf16-MFMA invmqn) and builds bf16 frags from f32 d/q directly
//      (qb16/db16/m2b16/m2all buffers deleted).
//    - relwq self-computes d/q norms with k_prep's EXACT lane partition and
//      shfl order -> rel/argmax/wq bit-identical to r10 (argmax risk: zero).
//    - gemm1 self-builds B from raw M (square+cvt inline).
//  K2 k_final = gemm2 fused with the full epilogue: tasks write normalized
//    out cols 0:50 / 150:200 / 200:250 directly (att-pair task computes both
//    d*wq and wq^2 GEMMs in one wave); 50 tail blocks assemble cols 50:150
//    from pmax2/psum2. G buffer deleted.

#define EPS 1e-6f
#define NEG_HUGE -3.4e38f

typedef __bf16 bf16x8 __attribute__((ext_vector_type(8)));
typedef float f32x16 __attribute__((ext_vector_type(16)));

// ---- ws offsets (floats) ----
constexpr size_t OFF_INVFPN = 0;        // [6400][50]
constexpr size_t OFF_INVMPN = 320000;
constexpr size_t OFF_INVAPN = 640000;
constexpr size_t OFF_INVXPN = 960000;
constexpr size_t OFF_INVMQN = 1280000;  // dead (maxpool self-computes); gemm1 still writes
constexpr size_t OFF_INVXQN = 1600000;  // [6400][50]
constexpr size_t OFF_INVFQN = 1920000;  // [32][50]
constexpr size_t OFF_IDX    = 1921600;  // int [6400]
constexpr size_t OFF_WQ     = 1928000;  // [32][200][200]
constexpr size_t OFF_PMAX2  = 3208000;  // [1600][256]
constexpr size_t OFF_PSUM2  = 3617600;  // [1600][256]
// end = 4,027,200 floats = 16.1 MB

struct MPShared {
  unsigned short qsh[128*216];  // 55296 B
  float m2sh[208];
  float iqsh[200];
};
struct RWShared {
  float relsh[2][8][256];
  float iqn[2][200];
  float idn[2][8];
  float redv[2][4][8][2];
  int   redi[2][4][8];
  float invrs[2][8];
};
union KShared { MPShared mp; RWShared rw; };

// K1: blocks [0,1600)=maxpool(b,c); [1600,2000)=relwq (2 units/block);
// [2000,2351)=gemm1 (8 wave-tasks/block, 2807 tasks).
__global__ __launch_bounds__(512,2) void k_main(
    const float* __restrict__ qR, const float* __restrict__ dR,
    const float* __restrict__ qL,
    const float* __restrict__ qMask, const float* __restrict__ dMask,
    const float* __restrict__ fM, const float* __restrict__ mM,
    const float* __restrict__ aM, const float* __restrict__ xM,
    float* __restrict__ invfpn, float* __restrict__ invmpn,
    float* __restrict__ invapn, float* __restrict__ invxpn,
    float* __restrict__ invmqn, float* __restrict__ invxqn,
    float* __restrict__ invfqn,
    float* __restrict__ wq, int* __restrict__ idxout,
    float* __restrict__ pmax2, float* __restrict__ psum2)
{
  __shared__ KShared sh;
  int tid = threadIdx.x;
  int blk = blockIdx.x;
  int w = tid >> 6, lane = tid & 63;
  int n = lane & 31, h = lane >> 5;

  if (blk < 1600) {
    // ================= maxpool role (r9 v6 core, self-normed) =================
    int b = blk / 50, c = blk % 50;
    if (tid < 52) {                       // m2sh = mpM[c]^2, zero-padded to 208
      int k = tid*4;
      float4 o = {0.f,0.f,0.f,0.f};
      if (k < 200) {
        float4 v = *(const float4*)(mM + c*200 + k);
        o.x=v.x*v.x; o.y=v.y*v.y; o.z=v.z*v.z; o.w=v.w*v.w;
      }
      *(float4*)(sh.mp.m2sh + k) = o;
    }
    __syncthreads();
    {                                     // iqsh[j] = rsqrt(sum q^2 M2), f32
      const float* qb = qR + b*40000;
      for (int j = w*25; j < w*25 + 25; j++) {
        const float* qr = qb + j*200;
        float s = 0.f;
        for (int k = lane; k < 200; k += 64) { float v = qr[k]; s = fmaf(v*v, sh.mp.m2sh[k], s); }
#pragma unroll
        for (int m = 32; m; m >>= 1) s += __shfl_xor(s, m);
        if (lane == 0) sh.mp.iqsh[j] = rsqrtf(fmaxf(s, EPS));
      }
    }
    // A = bf16(d) raw, resident whole kernel (launch_bounds(512,2) -> no remat)
    bf16x8 afrag[13];
    {
      int i = w*32 + n, ir = min(i, 199);
      const float* drow = dR + (size_t)(b*200 + ir)*200;
#pragma unroll
      for (int ks = 0; ks < 13; ks++) {
        int ko = ks*16 + h*8;
        bf16x8 af;
        if (ko < 200) {
          float4 a0 = *(const float4*)(drow + ko);
          float4 a1 = *(const float4*)(drow + ko + 4);
          af[0]=(__bf16)a0.x; af[1]=(__bf16)a0.y; af[2]=(__bf16)a0.z; af[3]=(__bf16)a0.w;
          af[4]=(__bf16)a1.x; af[5]=(__bf16)a1.y; af[6]=(__bf16)a1.z; af[7]=(__bf16)a1.w;
        } else {
#pragma unroll
          for (int z = 0; z < 8; z++) af[z] = (__bf16)0.0f;
        }
        afrag[ks] = af;
      }
    }
    float vm[16], vs[16];
#pragma unroll
    for (int r = 0; r < 16; r++) { vm[r] = NEG_HUGE; vs[r] = 0.f; }

    for (int jh = 0; jh < 2; jh++) {
      int nrows = jh ? 96 : 128;
      int njt   = jh ? 3 : 4;
      __syncthreads();                    // also covers iqsh completion (jh=0)
      {
        const float* qb = qR + b*40000;
        for (int s = tid; s < nrows*26; s += 512) {
          int r = s / 26, ch = s - r*26;
          int j = jh*128 + r;
          int k0 = ch*8;
          bf16x8 o;
          if (j < 200 && k0 < 200) {
            const float* qr = qb + (size_t)j*200 + k0;
            float4 v0 = *(const float4*)qr;
            float4 v1 = *(const float4*)(qr + 4);
            float iq = sh.mp.iqsh[j];
            o[0]=(__bf16)(v0.x*iq*sh.mp.m2sh[k0+0]); o[1]=(__bf16)(v0.y*iq*sh.mp.m2sh[k0+1]);
            o[2]=(__bf16)(v0.z*iq*sh.mp.m2sh[k0+2]); o[3]=(__bf16)(v0.w*iq*sh.mp.m2sh[k0+3]);
            o[4]=(__bf16)(v1.x*iq*sh.mp.m2sh[k0+4]); o[5]=(__bf16)(v1.y*iq*sh.mp.m2sh[k0+5]);
            o[6]=(__bf16)(v1.z*iq*sh.mp.m2sh[k0+6]); o[7]=(__bf16)(v1.w*iq*sh.mp.m2sh[k0+7]);
          } else {
#pragma unroll
            for (int z = 0; z < 8; z++) o[z] = (__bf16)0.0f;
          }
          *(bf16x8*)(sh.mp.qsh + r*216 + k0) = o;
        }
      }
      __syncthreads();
      for (int jt = 0; jt < njt; jt++) {
        f32x16 C;
#pragma unroll
        for (int z = 0; z < 16; z++) C[z] = 0.f;
        const unsigned short* bptr = sh.mp.qsh + (jt*32 + n)*216 + h*8;
#pragma unroll
        for (int ks = 0; ks < 13; ks++) {
          bf16x8 bf = *(const bf16x8*)(bptr + ks*16);
          C = __builtin_amdgcn_mfma_f32_32x32x16_bf16(afrag[ks], bf, C, 0, 0, 0);
        }
        bool jv = (jh*128 + jt*32 + n) < 200;
#pragma unroll
        for (int r = 0; r < 16; r++) {
          vm[r] = fmaxf(vm[r], jv ? C[r] : NEG_HUGE);
          vs[r] += C[r];
        }
      }
    }
#pragma unroll
    for (int r = 0; r < 16; r++) {
      float a = vm[r], s = vs[r];
#pragma unroll
      for (int m = 1; m <= 16; m <<= 1) { a = fmaxf(a, __shfl_xor(a, m)); s += __shfl_xor(s, m); }
      vm[r] = a; vs[r] = s;
    }
    if (n == 0) {
#pragma unroll
      for (int r = 0; r < 16; r++) {
        int i = w*32 + (r & 3) + 8*(r >> 2) + 4*h;
        pmax2[(size_t)blk*256 + i] = vm[r];
        psum2[(size_t)blk*256 + i] = vs[r];
      }
    }
  } else if (blk < 2000) {
    // ================= relwq role: two 256-thread units =================
    int u = tid >> 8;
    int tid2 = tid & 255;
    int unit = (blk - 1600)*2 + u;        // 0..799
    int b = unit / 25, i0 = (unit % 25)*8;
    int w2 = tid2 >> 6, l = lane;
    int j = tid2, jr = min(j, 199);
    bool jv = j < 200;
    const float* qb = qR + b*40000;
    const float* db = dR + (b*200 + i0)*200;

    // norms — k_prep's exact formula/order (bit-identical invqn/invdn)
    for (int jq = w2*50; jq < w2*50 + 50; jq++) {
      float4 v = {0.f,0.f,0.f,0.f};
      if (l < 50) v = *(const float4*)(qb + jq*200 + l*4);
      float s = fmaf(v.x,v.x, fmaf(v.y,v.y, fmaf(v.z,v.z, v.w*v.w)));
#pragma unroll
      for (int m = 32; m; m >>= 1) s += __shfl_xor(s, m);
      if (l == 0) sh.rw.iqn[u][jq] = rsqrtf(fmaxf(s, EPS));
    }
    if (w2 == 0) {
      for (int ii = 0; ii < 8; ii++) {
        float4 v = {0.f,0.f,0.f,0.f};
        if (l < 50) v = *(const float4*)(db + ii*200 + l*4);
        float s = fmaf(v.x,v.x, fmaf(v.y,v.y, fmaf(v.z,v.z, v.w*v.w)));
#pragma unroll
        for (int m = 32; m; m >>= 1) s += __shfl_xor(s, m);
        if (l == 0) sh.rw.idn[u][ii] = rsqrtf(fmaxf(s, EPS));
      }
    }
    __syncthreads();

    float acc[8];
#pragma unroll
    for (int ii = 0; ii < 8; ii++) acc[ii] = 0.f;
    const float* qrow = qb + jr*200;
    for (int k4 = 0; k4 < 200; k4 += 4) {
      float4 qv = *(const float4*)(qrow + k4);
#pragma unroll
      for (int ii = 0; ii < 8; ii++) {
        acc[ii] = fmaf(db[ii*200 + k4 + 0], qv.x, acc[ii]);
        acc[ii] = fmaf(db[ii*200 + k4 + 1], qv.y, acc[ii]);
        acc[ii] = fmaf(db[ii*200 + k4 + 2], qv.z, acc[ii]);
        acc[ii] = fmaf(db[ii*200 + k4 + 3], qv.w, acc[ii]);
      }
    }
    float iqnv = sh.rw.iqn[u][jr];
    float qm  = qMask[b*200 + jr];
    float rv[8];
#pragma unroll
    for (int ii = 0; ii < 8; ii++) {
      float idnv = sh.rw.idn[u][ii];
      float dm = dMask[b*200 + i0 + ii];
      float r = acc[ii]*iqnv*idnv*qm*dm;
      rv[ii] = r;
      sh.rw.relsh[u][ii][j] = jv ? r : 0.f;
    }
#pragma unroll
    for (int ii = 0; ii < 8; ii++) {
      float vmv = jv ? rv[ii] : NEG_HUGE;
      float vsv = jv ? rv[ii] : 0.f;
      int bj = jr;
#pragma unroll
      for (int m = 32; m; m >>= 1) {
        float ov = __shfl_xor(vmv, m);
        int   oj = __shfl_xor(bj, m);
        vsv += __shfl_xor(vsv, m);
        if (ov > vmv || (ov == vmv && oj < bj)) { vmv = ov; bj = oj; }  // first-max
      }
      if (l == 0) { sh.rw.redv[u][w2][ii][0] = vmv; sh.rw.redv[u][w2][ii][1] = vsv; sh.rw.redi[u][w2][ii] = bj; }
    }
    __syncthreads();
    if (tid2 < 8) {
      float bv = sh.rw.redv[u][0][tid2][0], ss = sh.rw.redv[u][0][tid2][1];
      int bj = sh.rw.redi[u][0][tid2];
      for (int w3 = 1; w3 < 4; w3++) {
        ss += sh.rw.redv[u][w3][tid2][1];
        float wv = sh.rw.redv[u][w3][tid2][0]; int wj = sh.rw.redi[u][w3][tid2];
        if (wv > bv || (wv == bv && wj < bj)) { bv = wv; bj = wj; }
      }
      sh.rw.invrs[u][tid2] = 1.f/(ss + EPS);
      idxout[b*200 + i0 + tid2] = bj;
    }
    __syncthreads();
    int kl = min(tid2, 199); bool kv = tid2 < 200;
    float acw[8];
#pragma unroll
    for (int ii = 0; ii < 8; ii++) acw[ii] = 0.f;
    for (int j0 = 0; j0 < 200; j0 += 4) {
      float qv0 = qb[(j0+0)*200 + kl];
      float qv1 = qb[(j0+1)*200 + kl];
      float qv2 = qb[(j0+2)*200 + kl];
      float qv3 = qb[(j0+3)*200 + kl];
#pragma unroll
      for (int ii = 0; ii < 8; ii++) {
        float4 rs = *(const float4*)&sh.rw.relsh[u][ii][j0];
        acw[ii] = fmaf(rs.x, qv0, acw[ii]);
        acw[ii] = fmaf(rs.y, qv1, acw[ii]);
        acw[ii] = fmaf(rs.z, qv2, acw[ii]);
        acw[ii] = fmaf(rs.w, qv3, acw[ii]);
      }
    }
#pragma unroll
    for (int ii = 0; ii < 8; ii++) {
      float v = acw[ii]*sh.rw.invrs[u][ii];
      if (kv) wq[(size_t)(b*200 + i0 + ii)*200 + tid2] = v;
    }
  } else {
    // ================= gemm1 role: nsq MFMA + rsqrt scatter =================
    int task = (blk - 2000)*8 + w;
    if (task < 2807) {
      int rt = task / 7, nt = task % 7;
      int row = rt*32 + n;
      const float* src;
      if (row < 6400)       src = dR + (size_t)row*200;
      else if (row < 12800) src = qR + (size_t)(row-6400)*200;
      else                  src = qL + (size_t)(row-12800)*200;

      bf16x8 afrag[13];
#pragma unroll
      for (int ks = 0; ks < 13; ks++) {
        int ko = ks*16 + h*8;
        bf16x8 af;
        if (ko < 200) {
          float4 a0 = *(const float4*)(src + ko);
          float4 a1 = *(const float4*)(src + ko + 4);
          af[0]=(__bf16)(a0.x*a0.x); af[1]=(__bf16)(a0.y*a0.y);
          af[2]=(__bf16)(a0.z*a0.z); af[3]=(__bf16)(a0.w*a0.w);
          af[4]=(__bf16)(a1.x*a1.x); af[5]=(__bf16)(a1.y*a1.y);
          af[6]=(__bf16)(a1.z*a1.z); af[7]=(__bf16)(a1.w*a1.w);
        } else {
#pragma unroll
          for (int z = 0; z < 8; z++) af[z] = (__bf16)0.0f;
        }
        afrag[ks] = af;
      }
      int cp = nt*32 + n;
      bool cpv = cp < 200;
      int mIdx = 0, cIdx = 0;
      const float* msrc = fM;
      if (cpv) {
        mIdx = cp / 50; cIdx = cp % 50;
        msrc = ((mIdx==0)?fM:(mIdx==1)?mM:(mIdx==2)?aM:xM) + cIdx*200;
      }
      f32x16 C;
#pragma unroll
      for (int z = 0; z < 16; z++) C[z] = 0.f;
#pragma unroll
      for (int ks = 0; ks < 13; ks++) {
        int ko = ks*16 + h*8;
        bf16x8 bf;
        if (cpv && ko < 200) {
          float4 b0 = *(const float4*)(msrc + ko);
          float4 b1 = *(const float4*)(msrc + ko + 4);
          bf[0]=(__bf16)(b0.x*b0.x); bf[1]=(__bf16)(b0.y*b0.y);
          bf[2]=(__bf16)(b0.z*b0.z); bf[3]=(__bf16)(b0.w*b0.w);
          bf[4]=(__bf16)(b1.x*b1.x); bf[5]=(__bf16)(b1.y*b1.y);
          bf[6]=(__bf16)(b1.z*b1.z); bf[7]=(__bf16)(b1.w*b1.w);
        } else {
#pragma unroll
          for (int z = 0; z < 8; z++) bf[z] = (__bf16)0.0f;
        }
        C = __builtin_amdgcn_mfma_f32_32x32x16_bf16(afrag[ks], bf, C, 0, 0, 0);
      }
      if (cpv) {
#pragma unroll
        for (int r = 0; r < 16; r++) {
          int grow = rt*32 + (r & 3) + 8*(r >> 2) + 4*h;
          float v = rsqrtf(fmaxf(C[r], EPS));
          if (grow < 6400) {
            if (mIdx == 0)      invfpn[grow*50 + cIdx] = v;
            else if (mIdx == 1) invmpn[grow*50 + cIdx] = v;
            else if (mIdx == 2) invapn[grow*50 + cIdx] = v;
            else                invxpn[grow*50 + cIdx] = v;
          } else if (grow < 12800) {
            int r2 = grow - 6400;
            if (mIdx == 1)      invmqn[cIdx*6400 + r2] = v;
            else if (mIdx == 3) invxqn[r2*50 + cIdx] = v;
          } else {
            if (mIdx == 0)      invfqn[(grow-12800)*50 + cIdx] = v;
          }
        }
      }
    }
  }
}

// K2: blocks [0,150) = gemm-final (8 wave-tasks/block; typ 0=full, 1=att-pair,
// 2=maxatt; writes normalized out cols directly); [150,200) = cols 50:150
// assembly from pmax2/psum2.
__global__ __launch_bounds__(512,2) void k_final(
    const float* __restrict__ dR, const float* __restrict__ qR,
    const float* __restrict__ qL, const float* __restrict__ wq,
    const int* __restrict__ idx,
    const float* __restrict__ fM, const float* __restrict__ aM,
    const float* __restrict__ xM,
    const float* __restrict__ invfpn, const float* __restrict__ invmpn,
    const float* __restrict__ invapn, const float* __restrict__ invxpn,
    const float* __restrict__ invfqn, const float* __restrict__ invxqn,
    const float* __restrict__ pmax2, const float* __restrict__ psum2,
    float* __restrict__ out)
{
  int tid = threadIdx.x;
  int blk = blockIdx.x;
  int w = tid >> 6, lane = tid & 63;
  int n = lane & 31, h = lane >> 5;
  if (blk < 150) {
    int gtask = blk*8 + w;                 // [0,1200)
    int typ = gtask / 400;
    int sub = gtask % 400;
    int rt = sub >> 1, nt = sub & 1;
    int row = rt*32 + n, bb = row / 200;
    int cc = nt*32 + n;
    bool ccv = cc < 50;
    const float* Bsrc = (typ == 0) ? fM : (typ == 1) ? aM : xM;
    const float* msrc = Bsrc + (ccv ? cc : 0)*200;

    bf16x8 bfrag[13];
#pragma unroll
    for (int ks = 0; ks < 13; ks++) {
      int ko = ks*16 + h*8;
      bf16x8 bf;
      if (ccv && ko < 200) {
        float4 b0 = *(const float4*)(msrc + ko);
        float4 b1 = *(const float4*)(msrc + ko + 4);
        bf[0]=(__bf16)(b0.x*b0.x); bf[1]=(__bf16)(b0.y*b0.y);
        bf[2]=(__bf16)(b0.z*b0.z); bf[3]=(__bf16)(b0.w*b0.w);
        bf[4]=(__bf16)(b1.x*b1.x); bf[5]=(__bf16)(b1.y*b1.y);
        bf[6]=(__bf16)(b1.z*b1.z); bf[7]=(__bf16)(b1.w*b1.w);
      } else {
#pragma unroll
        for (int z = 0; z < 8; z++) bf[z] = (__bf16)0.0f;
      }
      bfrag[ks] = bf;
    }

    auto buildA = [&](const float* s0, const float* s1, bf16x8* fr) {
#pragma unroll
      for (int ks = 0; ks < 13; ks++) {
        int ko = ks*16 + h*8;
        bf16x8 af;
        if (ko < 200) {
          float4 a0 = *(const float4*)(s0 + ko), a1 = *(const float4*)(s0 + ko + 4);
          float4 b0 = *(const float4*)(s1 + ko), b1 = *(const float4*)(s1 + ko + 4);
          af[0]=(__bf16)(a0.x*b0.x); af[1]=(__bf16)(a0.y*b0.y);
          af[2]=(__bf16)(a0.z*b0.z); af[3]=(__bf16)(a0.w*b0.w);
          af[4]=(__bf16)(a1.x*b1.x); af[5]=(__bf16)(a1.y*b1.y);
          af[6]=(__bf16)(a1.z*b1.z); af[7]=(__bf16)(a1.w*b1.w);
        } else {
#pragma unroll
          for (int z = 0; z < 8; z++) af[z] = (__bf16)0.0f;
        }
        fr[ks] = af;
      }
    };

    const float* s0 = dR + (size_t)row*200;
    const float* s1;
    if (typ == 0)      s1 = qL + (size_t)bb*200;
    else if (typ == 1) s1 = wq + (size_t)row*200;
    else               s1 = qR + (size_t)(bb*200 + idx[row])*200;

    bf16x8 afrag[13];
    buildA(s0, s1, afrag);
    f32x16 C1;
#pragma unroll
    for (int z = 0; z < 16; z++) C1[z] = 0.f;
#pragma unroll
    for (int ks = 0; ks < 13; ks++)
      C1 = __builtin_amdgcn_mfma_f32_32x32x16_bf16(afrag[ks], bfrag[ks], C1, 0, 0, 0);

    f32x16 C2;
#pragma unroll
    for (int z = 0; z < 16; z++) C2[z] = 0.f;
    if (typ == 1) {
      const float* s2 = wq + (size_t)row*200;
      buildA(s2, s2, afrag);
#pragma unroll
      for (int ks = 0; ks < 13; ks++)
        C2 = __builtin_amdgcn_mfma_f32_32x32x16_bf16(afrag[ks], bfrag[ks], C2, 0, 0, 0);
    }

    if (ccv) {
#pragma unroll
      for (int r = 0; r < 16; r++) {
        int grow = rt*32 + (r & 3) + 8*(r >> 2) + 4*h;
        int b2 = grow / 200;
        float o; int colbase;
        if (typ == 0) {
          o = C1[r]*invfpn[grow*50 + cc]*invfqn[b2*50 + cc]; colbase = 0;
        } else if (typ == 1) {
          o = C1[r]*invapn[grow*50 + cc]*rsqrtf(fmaxf(C2[r], EPS)); colbase = 150;
        } else {
          int jid = idx[grow];
          o = C1[r]*invxpn[grow*50 + cc]*invxqn[(b2*200 + jid)*50 + cc]; colbase = 200;
        }
        out[(size_t)grow*250 + colbase + cc] = o;
      }
    }
  } else {
    // cols 50:150 assembly
    int base = (blk - 150)*512 + tid;
    for (int e = base; e < 640000; e += 25600) {
      int row = e / 100, cl = e % 100;
      int b2 = row / 200, i2 = row % 200;
      int c2 = (cl < 50) ? cl : cl - 50;
      float pv = (cl < 50) ? pmax2[(size_t)(b2*50 + c2)*256 + i2]
                           : psum2[(size_t)(b2*50 + c2)*256 + i2]*(1.f/200.f);
      out[(size_t)row*250 + 50 + cl] = pv*invmpn[row*50 + c2];
    }
  }
}

extern "C" void kernel_launch(void* const* d_in, const int* in_sizes, int n_in,
                              void* d_out, int out_size, void* d_ws, size_t ws_size,
                              hipStream_t stream) {
  const float* qR = (const float*)d_in[0];
  const float* qL = (const float*)d_in[1];
  const float* qM = (const float*)d_in[2];
  const float* dR = (const float*)d_in[3];
  // d_in[4] = d_last: unused by the reference
  const float* dM = (const float*)d_in[5];
  const float* fullM = (const float*)d_in[6];
  const float* mpM   = (const float*)d_in[7];
  const float* attM  = (const float*)d_in[8];
  const float* xM    = (const float*)d_in[9];

  float* ws  = (float*)d_ws;
  float* out = (float*)d_out;

  float* invfpn = ws + OFF_INVFPN;
  float* invmpn = ws + OFF_INVMPN;
  float* invapn = ws + OFF_INVAPN;
  float* invxpn = ws + OFF_INVXPN;
  float* invmqn = ws + OFF_INVMQN;
  float* invxqn = ws + OFF_INVXQN;
  float* invfqn = ws + OFF_INVFQN;
  int*   idxp   = (int*)(ws + OFF_IDX);
  float* wqp    = ws + OFF_WQ;
  float* pmax2  = ws + OFF_PMAX2;
  float* psum2  = ws + OFF_PSUM2;

  k_main<<<2351, 512, 0, stream>>>(qR, dR, qL, qM, dM,
                                   fullM, mpM, attM, xM,
                                   invfpn, invmpn, invapn, invxpn,
                                   invmqn, invxqn, invfqn,
                                   wqp, idxp, pmax2, psum2);
  k_final<<<200, 512, 0, stream>>>(dR, qR, qL, wqp, idxp,
                                   fullM, attM, xM,
                                   invfpn, invmpn, invapn, invxpn,
                                   invfqn, invxqn, pmax2, psum2, out);
}

// Round 12
// 331.627 us; speedup vs baseline: 1.5754x; 1.5754x over previous
//
#include <hip/hip_runtime.h>
#include <math.h>

// MultiPerspectiveMatch on MI355X — round 12.
// r11 (2-kernel mega-fusion) regressed 248->522us with 4 confounded changes in
// the maxpool pole. Disciplined partial revert:
//  K2 k_big  = r10 VERBATIM (maxpool+gemm2, proven 105us).
//  K3 k_out  = r10 VERBATIM.
//  K1 k_front = r10 k_prep + r11's correctness-proven self-sufficient roles
//    (relwq w/ self-norms, gemm1 w/ inline-B), roles ordered relwq->gemm1->prep.
//    LDS 18.9KB (no 57KB union). Isolates those roles' perf at -1 launch.

#define EPS 1e-6f
#define NEG_HUGE -3.4e38f

typedef __bf16 bf16x8 __attribute__((ext_vector_type(8)));
typedef float f32x16 __attribute__((ext_vector_type(16)));

// ---- ws offsets (floats) ---- (r10 layout)
constexpr size_t OFF_M2ALL = 0;            // f32 [4][50][200] = 40,000
constexpr size_t OFF_M2B16 = 40000;        // bf16 [224][208] = 23,296 fl
constexpr size_t OFF_QB16  = 63296;        // bf16 [32][256][208] = 851,968 fl
constexpr size_t OFF_DB16  = 915264;       // bf16 [32][256][208] = 851,968 fl
constexpr size_t OFF_INVFPN= 1767232;      // [6400][50]
constexpr size_t OFF_INVMPN= 2087232;
constexpr size_t OFF_INVAPN= 2407232;
constexpr size_t OFF_INVXPN= 2727232;
constexpr size_t OFF_INVMQN= 3047232;      // [c(50)][6400]
constexpr size_t OFF_INVXQN= 3367232;      // [6400][50]
constexpr size_t OFF_INVFQN= 3687232;      // [32][50]
constexpr size_t OFF_IDX   = 3701632;      // int [6400]
constexpr size_t OFF_WQ    = 3708032;      // [32][200][200]
constexpr size_t OFF_G     = 4988032;      // [4][6400][50]
constexpr size_t OFF_PMAX2 = 6268032;      // [1600][256]
constexpr size_t OFF_PSUM2 = 6677632;      // [1600][256]
// end = 7,087,232 floats = 28.3 MB

struct RWShared {
  float relsh[2][8][256];
  float iqn[2][200];
  float idn[2][8];
  float redv[2][4][8][2];
  int   redi[2][4][8];
  float invrs[2][8];
};                                          // 18,880 B

// K1: blocks [0,400)=relwq (2 units/block, self-norms);
// [400,751)=gemm1 (8 wave-tasks/block, inline B);
// [751,2799)=prep rows (8 row-tasks/block); [2799,2890)=prep M2 tables.
__global__ __launch_bounds__(512) void k_front(
    const float* __restrict__ qR, const float* __restrict__ dR,
    const float* __restrict__ qL,
    const float* __restrict__ qMask, const float* __restrict__ dMask,
    const float* __restrict__ fM, const float* __restrict__ mM,
    const float* __restrict__ aM, const float* __restrict__ xM,
    unsigned short* __restrict__ qb16, unsigned short* __restrict__ db16,
    float* __restrict__ m2all, unsigned short* __restrict__ m2b16,
    float* __restrict__ invfpn, float* __restrict__ invmpn,
    float* __restrict__ invapn, float* __restrict__ invxpn,
    float* __restrict__ invmqn, float* __restrict__ invxqn,
    float* __restrict__ invfqn,
    float* __restrict__ wq, int* __restrict__ idxout)
{
  __shared__ RWShared sh;                   // used by relwq role only
  int tid = threadIdx.x;
  int blk = blockIdx.x;
  int w = tid >> 6, lane = tid & 63;
  int n = lane & 31, h = lane >> 5;

  if (blk < 400) {
    // ================= relwq role (r11-proven, self-norms) =================
    int u = tid >> 8;
    int tid2 = tid & 255;
    int unit = blk*2 + u;                   // 0..799
    int b = unit / 25, i0 = (unit % 25)*8;
    int w2 = tid2 >> 6, l = lane;
    int j = tid2, jr = min(j, 199);
    bool jv = j < 200;
    const float* qb = qR + b*40000;
    const float* db = dR + (b*200 + i0)*200;

    // norms — k_prep's exact formula/order (bit-identical invqn/invdn)
    for (int jq = w2*50; jq < w2*50 + 50; jq++) {
      float4 v = {0.f,0.f,0.f,0.f};
      if (l < 50) v = *(const float4*)(qb + jq*200 + l*4);
      float s = fmaf(v.x,v.x, fmaf(v.y,v.y, fmaf(v.z,v.z, v.w*v.w)));
#pragma unroll
      for (int m = 32; m; m >>= 1) s += __shfl_xor(s, m);
      if (l == 0) sh.iqn[u][jq] = rsqrtf(fmaxf(s, EPS));
    }
    if (w2 == 0) {
      for (int ii = 0; ii < 8; ii++) {
        float4 v = {0.f,0.f,0.f,0.f};
        if (l < 50) v = *(const float4*)(db + ii*200 + l*4);
        float s = fmaf(v.x,v.x, fmaf(v.y,v.y, fmaf(v.z,v.z, v.w*v.w)));
#pragma unroll
        for (int m = 32; m; m >>= 1) s += __shfl_xor(s, m);
        if (l == 0) sh.idn[u][ii] = rsqrtf(fmaxf(s, EPS));
      }
    }
    __syncthreads();

    float acc[8];
#pragma unroll
    for (int ii = 0; ii < 8; ii++) acc[ii] = 0.f;
    const float* qrow = qb + jr*200;
    for (int k4 = 0; k4 < 200; k4 += 4) {
      float4 qv = *(const float4*)(qrow + k4);
#pragma unroll
      for (int ii = 0; ii < 8; ii++) {
        acc[ii] = fmaf(db[ii*200 + k4 + 0], qv.x, acc[ii]);
        acc[ii] = fmaf(db[ii*200 + k4 + 1], qv.y, acc[ii]);
        acc[ii] = fmaf(db[ii*200 + k4 + 2], qv.z, acc[ii]);
        acc[ii] = fmaf(db[ii*200 + k4 + 3], qv.w, acc[ii]);
      }
    }
    float iqnv = sh.iqn[u][jr];
    float qm  = qMask[b*200 + jr];
    float rv[8];
#pragma unroll
    for (int ii = 0; ii < 8; ii++) {
      float idnv = sh.idn[u][ii];
      float dm = dMask[b*200 + i0 + ii];
      float r = acc[ii]*iqnv*idnv*qm*dm;
      rv[ii] = r;
      sh.relsh[u][ii][j] = jv ? r : 0.f;
    }
#pragma unroll
    for (int ii = 0; ii < 8; ii++) {
      float vmv = jv ? rv[ii] : NEG_HUGE;
      float vsv = jv ? rv[ii] : 0.f;
      int bj = jr;
#pragma unroll
      for (int m = 32; m; m >>= 1) {
        float ov = __shfl_xor(vmv, m);
        int   oj = __shfl_xor(bj, m);
        vsv += __shfl_xor(vsv, m);
        if (ov > vmv || (ov == vmv && oj < bj)) { vmv = ov; bj = oj; }  // first-max
      }
      if (l == 0) { sh.redv[u][w2][ii][0] = vmv; sh.redv[u][w2][ii][1] = vsv; sh.redi[u][w2][ii] = bj; }
    }
    __syncthreads();
    if (tid2 < 8) {
      float bv = sh.redv[u][0][tid2][0], ss = sh.redv[u][0][tid2][1];
      int bj = sh.redi[u][0][tid2];
      for (int w3 = 1; w3 < 4; w3++) {
        ss += sh.redv[u][w3][tid2][1];
        float wv = sh.redv[u][w3][tid2][0]; int wj = sh.redi[u][w3][tid2];
        if (wv > bv || (wv == bv && wj < bj)) { bv = wv; bj = wj; }
      }
      sh.invrs[u][tid2] = 1.f/(ss + EPS);
      idxout[b*200 + i0 + tid2] = bj;
    }
    __syncthreads();
    int kl = min(tid2, 199); bool kv = tid2 < 200;
    float acw[8];
#pragma unroll
    for (int ii = 0; ii < 8; ii++) acw[ii] = 0.f;
    for (int j0 = 0; j0 < 200; j0 += 4) {
      float qv0 = qb[(j0+0)*200 + kl];
      float qv1 = qb[(j0+1)*200 + kl];
      float qv2 = qb[(j0+2)*200 + kl];
      float qv3 = qb[(j0+3)*200 + kl];
#pragma unroll
      for (int ii = 0; ii < 8; ii++) {
        float4 rs = *(const float4*)&sh.relsh[u][ii][j0];
        acw[ii] = fmaf(rs.x, qv0, acw[ii]);
        acw[ii] = fmaf(rs.y, qv1, acw[ii]);
        acw[ii] = fmaf(rs.z, qv2, acw[ii]);
        acw[ii] = fmaf(rs.w, qv3, acw[ii]);
      }
    }
#pragma unroll
    for (int ii = 0; ii < 8; ii++) {
      float v = acw[ii]*sh.invrs[u][ii];
      if (kv) wq[(size_t)(b*200 + i0 + ii)*200 + tid2] = v;
    }
  } else if (blk < 751) {
    // ================= gemm1 role (r11-proven, inline B) =================
    int task = (blk - 400)*8 + w;
    if (task < 2807) {
      int rt = task / 7, nt = task % 7;
      int row = rt*32 + n;
      const float* src;
      if (row < 6400)       src = dR + (size_t)row*200;
      else if (row < 12800) src = qR + (size_t)(row-6400)*200;
      else                  src = qL + (size_t)(row-12800)*200;

      bf16x8 afrag[13];
#pragma unroll
      for (int ks = 0; ks < 13; ks++) {
        int ko = ks*16 + h*8;
        bf16x8 af;
        if (ko < 200) {
          float4 a0 = *(const float4*)(src + ko);
          float4 a1 = *(const float4*)(src + ko + 4);
          af[0]=(__bf16)(a0.x*a0.x); af[1]=(__bf16)(a0.y*a0.y);
          af[2]=(__bf16)(a0.z*a0.z); af[3]=(__bf16)(a0.w*a0.w);
          af[4]=(__bf16)(a1.x*a1.x); af[5]=(__bf16)(a1.y*a1.y);
          af[6]=(__bf16)(a1.z*a1.z); af[7]=(__bf16)(a1.w*a1.w);
        } else {
#pragma unroll
          for (int z = 0; z < 8; z++) af[z] = (__bf16)0.0f;
        }
        afrag[ks] = af;
      }
      int cp = nt*32 + n;
      bool cpv = cp < 200;
      int mIdx = 0, cIdx = 0;
      const float* msrc = fM;
      if (cpv) {
        mIdx = cp / 50; cIdx = cp % 50;
        msrc = ((mIdx==0)?fM:(mIdx==1)?mM:(mIdx==2)?aM:xM) + cIdx*200;
      }
      f32x16 C;
#pragma unroll
      for (int z = 0; z < 16; z++) C[z] = 0.f;
#pragma unroll
      for (int ks = 0; ks < 13; ks++) {
        int ko = ks*16 + h*8;
        bf16x8 bf;
        if (cpv && ko < 200) {
          float4 b0 = *(const float4*)(msrc + ko);
          float4 b1 = *(const float4*)(msrc + ko + 4);
          bf[0]=(__bf16)(b0.x*b0.x); bf[1]=(__bf16)(b0.y*b0.y);
          bf[2]=(__bf16)(b0.z*b0.z); bf[3]=(__bf16)(b0.w*b0.w);
          bf[4]=(__bf16)(b1.x*b1.x); bf[5]=(__bf16)(b1.y*b1.y);
          bf[6]=(__bf16)(b1.z*b1.z); bf[7]=(__bf16)(b1.w*b1.w);
        } else {
#pragma unroll
          for (int z = 0; z < 8; z++) bf[z] = (__bf16)0.0f;
        }
        C = __builtin_amdgcn_mfma_f32_32x32x16_bf16(afrag[ks], bf, C, 0, 0, 0);
      }
      if (cpv) {
#pragma unroll
        for (int r = 0; r < 16; r++) {
          int grow = rt*32 + (r & 3) + 8*(r >> 2) + 4*h;
          float v = rsqrtf(fmaxf(C[r], EPS));
          if (grow < 6400) {
            if (mIdx == 0)      invfpn[grow*50 + cIdx] = v;
            else if (mIdx == 1) invmpn[grow*50 + cIdx] = v;
            else if (mIdx == 2) invapn[grow*50 + cIdx] = v;
            else                invxpn[grow*50 + cIdx] = v;
          } else if (grow < 12800) {
            int r2 = grow - 6400;
            if (mIdx == 1)      invmqn[cIdx*6400 + r2] = v;
            else if (mIdx == 3) invxqn[r2*50 + cIdx] = v;
          } else {
            if (mIdx == 0)      invfqn[(grow-12800)*50 + cIdx] = v;
          }
        }
      }
    }
  } else if (blk < 2799) {
    // ================= prep rows role (r10 k_prep, 8 tasks/block) =========
    int task = (blk - 751)*8 + w;          // 0..16383
    int l = lane;
    int isQ = task >= 8192;
    int r = isQ ? task - 8192 : task;      // b*256 + j
    int b = r >> 8, j = r & 255;
    unsigned short* dst = (isQ ? qb16 : db16) + (size_t)r*208;
    if (j < 200) {
      const float* src = (isQ ? qR : dR) + (size_t)(b*200 + j)*200;
      float4 v = {0.f,0.f,0.f,0.f};
      if (l < 50) v = *(const float4*)(src + l*4);
      if (l < 52) {
        ushort4 o = {0,0,0,0};
        if (l < 50) {
          __bf16 h0=(__bf16)v.x, h1=(__bf16)v.y, h2=(__bf16)v.z, h3=(__bf16)v.w;
          o.x = *(unsigned short*)&h0; o.y = *(unsigned short*)&h1;
          o.z = *(unsigned short*)&h2; o.w = *(unsigned short*)&h3;
        }
        *(ushort4*)(dst + l*4) = o;
      }
    } else {
      if (l < 52) { ushort4 z = {0,0,0,0}; *(ushort4*)(dst + l*4) = z; }
    }
  } else {
    // ================= prep M2 tables role =================
    int i = (blk - 2799)*512 + tid;        // < 46592
    if (i < 40000) {
      int m = i / 10000, r = i % 10000;
      const float* s = (m==0)?fM:(m==1)?mM:(m==2)?aM:xM;
      float v = s[r];
      m2all[i] = v*v;
    }
    if (i < 224*208) {
      int row = i / 208, k = i % 208;
      unsigned short o = 0;
      if (row < 200 && k < 200) {
        int m = row / 50, c = row % 50;
        const float* s = (m==0)?fM:(m==1)?mM:(m==2)?aM:xM;
        float v = s[c*200 + k];
        __bf16 hh = (__bf16)(v*v);
        o = *(unsigned short*)&hh;
      }
      m2b16[i] = o;
    }
  }
}

// K2: r10 k_big VERBATIM. blocks [0,1600)=maxpool; [1600,1800)=gemm2.
__global__ __launch_bounds__(512,2) void k_big(
    const unsigned short* __restrict__ db16, const unsigned short* __restrict__ qb16,
    const float* __restrict__ m2all, const float* __restrict__ invmqn,
    float* __restrict__ pmax2, float* __restrict__ psum2,
    const float* __restrict__ dR, const float* __restrict__ qR,
    const float* __restrict__ qL, const float* __restrict__ wq,
    const int* __restrict__ idx, const unsigned short* __restrict__ m2b16,
    float* __restrict__ G)
{
  int tid = threadIdx.x;
  int w = tid >> 6, lane = tid & 63;
  int n = lane & 31, h = lane >> 5;
  if (blockIdx.x < 1600) {
    __shared__ __align__(16) unsigned short qsh[128*216];  // 55296 B
    int b = blockIdx.x / 50, c = blockIdx.x % 50;
    const float* M2 = m2all + 10000 + c*200;
    const unsigned short* dbp = db16 + (size_t)(b*256 + w*32 + n)*208 + h*8;

    bf16x8 afrag[13];
#pragma unroll
    for (int ks = 0; ks < 13; ks++) afrag[ks] = *(const bf16x8*)(dbp + ks*16);

    float vm[16], vs[16];
#pragma unroll
    for (int r = 0; r < 16; r++) { vm[r] = NEG_HUGE; vs[r] = 0.f; }

    for (int jh = 0; jh < 2; jh++) {
      int nrows = jh ? 96 : 128;
      int njt   = jh ? 3 : 4;
      __syncthreads();
      {
        const unsigned short* src = qb16 + (size_t)(b*256 + jh*128)*208;
        const float* iqb = invmqn + c*6400 + b*200;
        for (int s = tid; s < nrows*26; s += 512) {
          int r = s / 26, ch = s - r*26;
          int j = jh*128 + r;
          float iq = (j < 200) ? iqb[j] : 0.f;
          int k0 = ch*8;
          bf16x8 v = *(const bf16x8*)(src + (size_t)r*208 + k0);
          float4 m0 = *(const float4*)(M2 + k0);     // k0=200 reads past-row
          float4 m1 = *(const float4*)(M2 + k0 + 4); // data: finite, x0=0. ok
          bf16x8 o;
          o[0] = (__bf16)((float)v[0]*iq*m0.x); o[1] = (__bf16)((float)v[1]*iq*m0.y);
          o[2] = (__bf16)((float)v[2]*iq*m0.z); o[3] = (__bf16)((float)v[3]*iq*m0.w);
          o[4] = (__bf16)((float)v[4]*iq*m1.x); o[5] = (__bf16)((float)v[5]*iq*m1.y);
          o[6] = (__bf16)((float)v[6]*iq*m1.z); o[7] = (__bf16)((float)v[7]*iq*m1.w);
          *(bf16x8*)(qsh + r*216 + k0) = o;
        }
      }
      __syncthreads();

      for (int jt = 0; jt < njt; jt++) {
        f32x16 C;
#pragma unroll
        for (int z = 0; z < 16; z++) C[z] = 0.f;
        const unsigned short* bptr = qsh + (jt*32 + n)*216 + h*8;
#pragma unroll
        for (int ks = 0; ks < 13; ks++) {
          bf16x8 bf = *(const bf16x8*)(bptr + ks*16);
          C = __builtin_amdgcn_mfma_f32_32x32x16_bf16(afrag[ks], bf, C, 0, 0, 0);
        }
        bool jv = (jh*128 + jt*32 + n) < 200;
#pragma unroll
        for (int r = 0; r < 16; r++) {
          vm[r] = fmaxf(vm[r], jv ? C[r] : NEG_HUGE);
          vs[r] += C[r];
        }
      }
    }

#pragma unroll
    for (int r = 0; r < 16; r++) {
      float a = vm[r], s = vs[r];
#pragma unroll
      for (int m = 1; m <= 16; m <<= 1) {
        a = fmaxf(a, __shfl_xor(a, m));
        s += __shfl_xor(s, m);
      }
      vm[r] = a; vs[r] = s;
    }
    if (n == 0) {
#pragma unroll
      for (int r = 0; r < 16; r++) {
        int i = w*32 + (r & 3) + 8*(r >> 2) + 4*h;
        pmax2[(size_t)blockIdx.x*256 + i] = vm[r];
        psum2[(size_t)blockIdx.x*256 + i] = vs[r];
      }
    }
  } else {
    int task = (blockIdx.x - 1600)*8 + w;    // [0,1600)
    int mp = task / 400;
    int sub = task % 400;
    int rt = sub >> 1, nt = sub & 1;
    int row = rt*32 + n;                     // < 6400
    int bb = row / 200;
    int msel = (mp == 0) ? 0 : (mp == 3) ? 3 : 2;

    const float* s0 = dR + (size_t)row*200;
    const float* s1;
    if (mp == 0)      s1 = qL + (size_t)bb*200;
    else if (mp == 1) s1 = wq + (size_t)row*200;
    else if (mp == 2) { s0 = wq + (size_t)row*200; s1 = s0; }
    else              s1 = qR + (size_t)(bb*200 + idx[row])*200;

    bf16x8 afrag[13];
#pragma unroll
    for (int ks = 0; ks < 13; ks++) {
      int ko = ks*16 + h*8;
      bf16x8 af;
      if (ko < 200) {
        float4 a0 = *(const float4*)(s0 + ko);
        float4 a1 = *(const float4*)(s0 + ko + 4);
        float4 b0 = *(const float4*)(s1 + ko);
        float4 b1 = *(const float4*)(s1 + ko + 4);
        af[0] = (__bf16)(a0.x*b0.x); af[1] = (__bf16)(a0.y*b0.y);
        af[2] = (__bf16)(a0.z*b0.z); af[3] = (__bf16)(a0.w*b0.w);
        af[4] = (__bf16)(a1.x*b1.x); af[5] = (__bf16)(a1.y*b1.y);
        af[6] = (__bf16)(a1.z*b1.z); af[7] = (__bf16)(a1.w*b1.w);
      } else {
#pragma unroll
        for (int z = 0; z < 8; z++) af[z] = (__bf16)0.0f;
      }
      afrag[ks] = af;
    }

    f32x16 C;
#pragma unroll
    for (int z = 0; z < 16; z++) C[z] = 0.f;
    const unsigned short* bp = m2b16 + (size_t)(msel*50 + nt*32 + n)*208 + h*8;
#pragma unroll
    for (int ks = 0; ks < 13; ks++) {
      bf16x8 bf = *(const bf16x8*)(bp + ks*16);
      C = __builtin_amdgcn_mfma_f32_32x32x16_bf16(afrag[ks], bf, C, 0, 0, 0);
    }
    int cc = nt*32 + n;
    if (cc < 50) {
#pragma unroll
      for (int r = 0; r < 16; r++) {
        int mrow = (r & 3) + 8*(r >> 2) + 4*h;
        G[(size_t)(mp*6400 + rt*32 + mrow)*50 + cc] = C[r];
      }
    }
  }
}

// K3: r10 k_out VERBATIM.
__global__ void k_out(
    const float* __restrict__ G, const float* __restrict__ pmax2,
    const float* __restrict__ psum2, const float* __restrict__ invfpn,
    const float* __restrict__ invmpn, const float* __restrict__ invapn,
    const float* __restrict__ invxpn, const float* __restrict__ invfqn,
    const float* __restrict__ invxqn, const int* __restrict__ idx,
    float* __restrict__ out)
{
  int row = blockIdx.x;
  int l = threadIdx.x;
  if (l >= 250) return;
  int b = row / 200, i = row % 200;
  int seg = l / 50, c = l % 50;
  float o;
  if (seg == 0) {
    o = G[(size_t)(0*6400 + row)*50 + c] * invfpn[row*50 + c] * invfqn[b*50 + c];
  } else if (seg == 1) {
    o = pmax2[(size_t)(b*50 + c)*256 + i] * invmpn[row*50 + c];
  } else if (seg == 2) {
    o = psum2[(size_t)(b*50 + c)*256 + i] * invmpn[row*50 + c] * (1.f/200.f);
  } else if (seg == 3) {
    o = G[(size_t)(1*6400 + row)*50 + c] * invapn[row*50 + c]
        * rsqrtf(fmaxf(G[(size_t)(2*6400 + row)*50 + c], EPS));
  } else {
    int jid = idx[row];
    o = G[(size_t)(3*6400 + row)*50 + c] * invxpn[row*50 + c]
        * invxqn[(b*200 + jid)*50 + c];
  }
  out[(size_t)row*250 + l] = o;
}

extern "C" void kernel_launch(void* const* d_in, const int* in_sizes, int n_in,
                              void* d_out, int out_size, void* d_ws, size_t ws_size,
                              hipStream_t stream) {
  const float* qR = (const float*)d_in[0];
  const float* qL = (const float*)d_in[1];
  const float* qM = (const float*)d_in[2];
  const float* dR = (const float*)d_in[3];
  // d_in[4] = d_last: unused by the reference
  const float* dM = (const float*)d_in[5];
  const float* fullM = (const float*)d_in[6];
  const float* mpM   = (const float*)d_in[7];
  const float* attM  = (const float*)d_in[8];
  const float* xM    = (const float*)d_in[9];

  float* ws  = (float*)d_ws;
  float* out = (float*)d_out;

  float* m2all  = ws + OFF_M2ALL;
  unsigned short* m2b16 = (unsigned short*)(ws + OFF_M2B16);
  unsigned short* qb16 = (unsigned short*)(ws + OFF_QB16);
  unsigned short* db16 = (unsigned short*)(ws + OFF_DB16);
  float* invfpn = ws + OFF_INVFPN;
  float* invmpn = ws + OFF_INVMPN;
  float* invapn = ws + OFF_INVAPN;
  float* invxpn = ws + OFF_INVXPN;
  float* invmqn = ws + OFF_INVMQN;
  float* invxqn = ws + OFF_INVXQN;
  float* invfqn = ws + OFF_INVFQN;
  int*   idxp   = (int*)(ws + OFF_IDX);
  float* wqp    = ws + OFF_WQ;
  float* G      = ws + OFF_G;
  float* pmax2  = ws + OFF_PMAX2;
  float* psum2  = ws + OFF_PSUM2;

  k_front<<<2890, 512, 0, stream>>>(qR, dR, qL, qM, dM,
                                    fullM, mpM, attM, xM,
                                    qb16, db16, m2all, m2b16,
                                    invfpn, invmpn, invapn, invxpn,
                                    invmqn, invxqn, invfqn,
                                    wqp, idxp);
  k_big<<<1800, 512, 0, stream>>>(db16, qb16, m2all, invmqn, pmax2, psum2,
                                  dR, qR, qL, wqp, idxp, m2b16, G);
  k_out<<<6400, 256, 0, stream>>>(G, pmax2, psum2, invfpn, invmpn, invapn,
                                  invxpn, invfqn, invxqn, idxp, out);
}